// Round 1
// baseline (575.265 us; speedup 1.0000x reference)
//
#include <hip/hip_runtime.h>
#include <math.h>

#define H 4096
#define E 64
#define T_TOTAL 32768
#define TB 64        // tokens per block
#define HK 128       // K-chunk in floats
#define NTHREADS 256

// d_out layout (floats):
//   logits : [0, 2097152)            = [4,8192,64]
//   weights: [2097152, 2162688)      = [32768,2]
//   indices: [2162688, 2228224)      = [32768,2] (written as float values)
#define OFF_W 2097152
#define OFF_I 2162688

__global__ __launch_bounds__(NTHREADS, 2)
void moe_router_kernel(const float* __restrict__ x,
                       const float* __restrict__ W,
                       float* __restrict__ out)
{
    // Swizzled W chunk: row e, real column c4 (float4 units) stored at
    // column c4 ^ ((e>>1)&7). 32 KB -> 2 blocks/CU fits easily.
    __shared__ float ws[E * HK];

    const int tid = threadIdx.x;
    const int tx  = tid & 31;      // expert-pair group: experts 2tx, 2tx+1
    const int ty  = tid >> 5;      // token group: tokens ty*8 .. ty*8+7
    const int tok0 = blockIdx.x * TB;
    const int e0  = tx * 2;
    const int swz = tx & 7;        // == ((e0>>1)&7) == (((e0+1)>>1)&7)

    const float* xr = x + (size_t)(tok0 + ty * 8) * H;

    float acc[8][2];
#pragma unroll
    for (int i = 0; i < 8; ++i) { acc[i][0] = 0.f; acc[i][1] = 0.f; }

    for (int kc = 0; kc < H / HK; ++kc) {
        const int hb = kc * HK;

        // ---- stage W chunk into LDS (64 rows x 32 float4), swizzled ----
        __syncthreads();   // protect ws from previous iteration's readers
#pragma unroll
        for (int k = 0; k < 8; ++k) {
            int g  = tid + k * NTHREADS;     // 0..2047
            int e  = g >> 5;                 // 0..63
            int c4 = g & 31;                 // 0..31
            float4 v = *(const float4*)(W + (size_t)e * H + hb + (c4 << 2));
            int c4s = c4 ^ ((e >> 1) & 7);
            *(float4*)(ws + e * HK + (c4s << 2)) = v;
        }
        __syncthreads();

        // ---- compute: 32 float4 K-steps ----
        float4 xv[8];
#pragma unroll
        for (int i = 0; i < 8; ++i)
            xv[i] = *(const float4*)(xr + (size_t)i * H + hb);

        for (int h4 = 0; h4 < HK / 4; ++h4) {
            // prefetch next step's x (wraps harmlessly to col 0 at h4==31)
            float4 xn[8];
            const int hnext = hb + (((h4 + 1) & 31) << 2);
#pragma unroll
            for (int i = 0; i < 8; ++i)
                xn[i] = *(const float4*)(xr + (size_t)i * H + hnext);

            const int col = ((h4 ^ swz) << 2);
            const float4 wv0 = *(const float4*)(ws + e0 * HK + col);
            const float4 wv1 = *(const float4*)(ws + (e0 + 1) * HK + col);

#pragma unroll
            for (int i = 0; i < 8; ++i) {
                float a0 = acc[i][0], a1 = acc[i][1];
                a0 = fmaf(xv[i].x, wv0.x, a0);
                a0 = fmaf(xv[i].y, wv0.y, a0);
                a0 = fmaf(xv[i].z, wv0.z, a0);
                a0 = fmaf(xv[i].w, wv0.w, a0);
                a1 = fmaf(xv[i].x, wv1.x, a1);
                a1 = fmaf(xv[i].y, wv1.y, a1);
                a1 = fmaf(xv[i].z, wv1.z, a1);
                a1 = fmaf(xv[i].w, wv1.w, a1);
                acc[i][0] = a0; acc[i][1] = a1;
            }
#pragma unroll
            for (int i = 0; i < 8; ++i) xv[i] = xn[i];
        }
    }

    // ---- epilogue: logits to global + LDS tile for top-2 ----
    __syncthreads();                       // done reading ws as W
    float* lt = ws;                        // reuse as [64][65] logits tile
#pragma unroll
    for (int i = 0; i < 8; ++i) {
        const int t = ty * 8 + i;
        lt[t * 65 + e0]     = acc[i][0];
        lt[t * 65 + e0 + 1] = acc[i][1];
        float2 o; o.x = acc[i][0]; o.y = acc[i][1];
        *(float2*)(out + (size_t)(tok0 + t) * E + e0) = o;
    }
    __syncthreads();

    if (tid < TB) {
        const float* row = lt + tid * 65;
        float v1 = -INFINITY, v2 = -INFINITY;
        int i1 = 0, i2 = 0;
        for (int e = 0; e < E; ++e) {
            float v = row[e];
            if (v > v1)      { v2 = v1; i2 = i1; v1 = v; i1 = e; }
            else if (v > v2) { v2 = v;  i2 = e; }
        }
        // softmax->top2->renorm == sigmoid of logit gap (Z cancels)
        float ee = expf(v2 - v1);          // <= 1
        float w1 = 1.0f / (1.0f + ee);
        float w2 = ee * w1;

        const size_t tok = (size_t)tok0 + tid;
        out[OFF_W + tok * 2]     = w1;
        out[OFF_W + tok * 2 + 1] = w2;
        out[OFF_I + tok * 2]     = (float)i1;
        out[OFF_I + tok * 2 + 1] = (float)i2;
    }
}

extern "C" void kernel_launch(void* const* d_in, const int* in_sizes, int n_in,
                              void* d_out, int out_size, void* d_ws, size_t ws_size,
                              hipStream_t stream) {
    const float* x = (const float*)d_in[0];
    const float* W = (const float*)d_in[1];
    float* out = (float*)d_out;

    dim3 grid(T_TOTAL / TB);   // 512 blocks
    dim3 block(NTHREADS);
    moe_router_kernel<<<grid, block, 0, stream>>>(x, W, out);
}